// Round 13
// baseline (1733.706 us; speedup 1.0000x reference)
//
#include <hip/hip_runtime.h>
#include <stdint.h>
#include <math.h>

#define BB 8
#define NN 16384
#define CC 13
#define GG 512
#define KK 32

#define NEIGH_ELEMS (BB*GG*KK*CC)   // 1,703,936

// ---------------------------------------------------------------------------
// DPP wave(64) arg-reductions: 6 VALU stages, result valid in LANE 63 only.
// bound_ctrl=false, old=self: invalid lanes combine with themselves (no-op
// for idempotent combine). Strict compare + lower-index tiebreak is
// commutative+associative -> tree exact. VALU pipe, no DS latency.
// ---------------------------------------------------------------------------
__device__ __forceinline__ void wave_argmax_dpp(float& v, int& p) {
    int vi = __float_as_int(v);
    int pi = p;
#define ARGMAX_STAGE(CTRL)                                                   \
    {                                                                        \
        int nv = __builtin_amdgcn_update_dpp(vi, vi, CTRL, 0xF, 0xF, false); \
        int np = __builtin_amdgcn_update_dpp(pi, pi, CTRL, 0xF, 0xF, false); \
        float a = __int_as_float(nv);                                        \
        float b = __int_as_float(vi);                                        \
        if (a > b || (a == b && np < pi)) { vi = nv; pi = np; }              \
    }
    ARGMAX_STAGE(0x111)  // row_shr:1
    ARGMAX_STAGE(0x112)  // row_shr:2
    ARGMAX_STAGE(0x114)  // row_shr:4
    ARGMAX_STAGE(0x118)  // row_shr:8
    ARGMAX_STAGE(0x142)  // row_bcast:15
    ARGMAX_STAGE(0x143)  // row_bcast:31
#undef ARGMAX_STAGE
    v = __int_as_float(vi);
    p = pi;
}

__device__ __forceinline__ void wave_argmin_dpp(float& v, int& p) {
    int vi = __float_as_int(v);
    int pi = p;
#define ARGMIN_STAGE(CTRL)                                                   \
    {                                                                        \
        int nv = __builtin_amdgcn_update_dpp(vi, vi, CTRL, 0xF, 0xF, false); \
        int np = __builtin_amdgcn_update_dpp(pi, pi, CTRL, 0xF, 0xF, false); \
        float a = __int_as_float(nv);                                        \
        float b = __int_as_float(vi);                                        \
        if (a < b || (a == b && np < pi)) { vi = nv; pi = np; }              \
    }
    ARGMIN_STAGE(0x111)  // row_shr:1
    ARGMIN_STAGE(0x112)  // row_shr:2
    ARGMIN_STAGE(0x114)  // row_shr:4
    ARGMIN_STAGE(0x118)  // row_shr:8
    ARGMIN_STAGE(0x142)  // row_bcast:15
    ARGMIN_STAGE(0x143)  // row_bcast:31
#undef ARGMIN_STAGE
    v = __int_as_float(vi);
    p = pi;
}

// Relaxed agent-scope 64-bit mailbox ops. Scope guarantees the access is
// serviced at the device coherence point (cross-XCD visible); the packed
// word carries tag+payload so no ordering fences are needed.
__device__ __forceinline__ unsigned long long mbox_load(const unsigned long long* p) {
    return __hip_atomic_load(p, __ATOMIC_RELAXED, __HIP_MEMORY_SCOPE_AGENT);
}
__device__ __forceinline__ void mbox_store(unsigned long long* p, unsigned long long v) {
    __hip_atomic_store(p, v, __ATOMIC_RELAXED, __HIP_MEMORY_SCOPE_AGENT);
}

// ---------------------------------------------------------------------------
// Pack: x[B,N,13] (fp32) -> f32 SoA planes px,py,pz (channels 4..6).
// Also zeroes the 32 fps mailbox slots (they live in d_out; knn overwrites
// that region later, and stream order makes this race-free).
// ---------------------------------------------------------------------------
__global__ void pack_kernel(const float* __restrict__ x,
                            float* __restrict__ px, float* __restrict__ py,
                            float* __restrict__ pz,
                            unsigned long long* __restrict__ mbox) {
    int i = blockIdx.x * blockDim.x + threadIdx.x;
    if (blockIdx.x == 0 && threadIdx.x < 32) mbox[threadIdx.x * 8] = 0ull;
    if (i >= BB * NN) return;
    const float* p = x + (size_t)i * CC + 4;
    px[i] = p[0]; py[i] = p[1]; pz[i] = p[2];
}

// ---------------------------------------------------------------------------
// FPS v8: TWO blocks per batch (16 blocks), 1024 threads, 8 points/thread.
// R10 post-mortem: named scalars (v7) produced codegen identical to arrays
// (VGPR 52, 1405us == v6) -> the backend's RA enforces a <=64-reg budget for
// 1024-thread blocks regardless of launch_bounds/waves_per_eu, spilling the
// 64-reg state in every 16-pt/thread variant (44/52 regs, ~3x instruction
// bloat, 72% per-CU VALUBusy on spill traffic). v8 stops fighting: 8
// pts/thread = 32 persistent regs + ~20 temps fits UNDER the ceiling, and
// per-CU compute halves. Cross-block argmax exchange per step via one
// packed u64 mailbox in d_out: tag(g)<<46 | f32bits<<14 | idx. Relaxed
// agent-scope atomics; tag match => payload valid (single word). Lockstep
// exchange makes stale tags (prev step / prev run) unmatchable; pack zeroes
// slots each run; 2^26-poll guard prevents hangs. Tie-break: ascending scan,
// strict compare, lower flat index at every level == np.argmax first-occur.
// fp32 distance math verbatim (bit-exact).
// ---------------------------------------------------------------------------
__global__ __launch_bounds__(1024)
void fps_kernel(const float* __restrict__ px,
                const float* __restrict__ py,
                const float* __restrict__ pz,
                float* __restrict__ centers,
                unsigned long long* __restrict__ mbox) {
    const int blk = blockIdx.x;
    const int b = blk & 7;        // batch (round-robins XCDs)
    const int k = blk >> 3;       // half: 0 or 1
    const int t = threadIdx.x;
    const int base = k << 13;     // k*8192
    const float* PX = px + b * NN;
    const float* PY = py + b * NN;
    const float* PZ = pz + b * NN;

    // slot(b,k,par) = ((b*4 + k*2 + par) * 8) u64s -> 64B stride/slot
    unsigned long long* my_base  = mbox + (((b << 2) | (k << 1)) << 3);
    unsigned long long* oth_base = mbox + (((b << 2) | ((k ^ 1) << 1)) << 3);

#define DECLPT(i) float x##i, y##i, z##i, md##i;
    DECLPT(0) DECLPT(1) DECLPT(2) DECLPT(3)
    DECLPT(4) DECLPT(5) DECLPT(6) DECLPT(7)
#undef DECLPT

#define INITPT(i)                                                            \
    {                                                                        \
        int pos = base + t + (i << 10);                                      \
        x##i = PX[pos]; y##i = PY[pos]; z##i = PZ[pos];                      \
        md##i = 1e10f; /* init_d = 10000000000.0 */                          \
        asm volatile("" : "+v"(x##i), "+v"(y##i), "+v"(z##i));               \
    }
    INITPT(0) INITPT(1) INITPT(2) INITPT(3)
    INITPT(4) INITPT(5) INITPT(6) INITPT(7)
#undef INITPT

    __shared__ float s_v[2][16];
    __shared__ int   s_p[2][16];

    int wp = 0;   // current center index (uniform across BOTH blocks)
    if (k == 0 && t == 0) {
        float* oc = centers + (size_t)b * GG * 3;
        oc[0] = PX[0]; oc[1] = PY[0]; oc[2] = PZ[0];
    }

    for (int g = 1; g < GG; ++g) {
        // scalar broadcast load of current center coords (uniform index)
        int swp = __builtin_amdgcn_readfirstlane(wp);
        float lx = PX[swp], ly = PY[swp], lz = PZ[swp];
        float bv = -1.0f;
        int bi = 0;   // best local point index 0..7 (compile-time consts)
#define STEPPT(i)                                                            \
    {                                                                        \
        float e0 = __fsub_rn(x##i, lx);                                      \
        float e1 = __fsub_rn(y##i, ly);                                      \
        float e2 = __fsub_rn(z##i, lz);                                      \
        float d  = __fadd_rn(__fadd_rn(__fmul_rn(e0, e0), __fmul_rn(e1, e1)),\
                             __fmul_rn(e2, e2));                             \
        float m = fminf(md##i, d); /* np.minimum */                          \
        md##i = m;                                                           \
        if (m > bv) { bv = m; bi = i; }                                      \
    }
        STEPPT(0) STEPPT(1) STEPPT(2) STEPPT(3)
        STEPPT(4) STEPPT(5) STEPPT(6) STEPPT(7)
#undef STEPPT
        int bp = base + t + (bi << 10);   // global flat pos, ascending in i
        wave_argmax_dpp(bv, bp);          // result in lane 63
        int par = g & 1;
        if ((t & 63) == 63) { s_v[par][t >> 6] = bv; s_p[par][t >> 6] = bp; }
        __syncthreads();
        // block-local best: redundant 16-partial scan by every thread
        float lv = s_v[par][0]; int lp = s_p[par][0];
#pragma unroll
        for (int q = 1; q < 16; ++q) {
            float qv = s_v[par][q]; int qp = s_p[par][q];
            if (qv > lv || (qv == lv && qp < lp)) { lv = qv; lp = qp; }
        }
        // publish my half's best, then spin for partner's (all threads spin;
        // same uniform address -> one request per wave per poll)
        if (t == 0) {
            unsigned long long pk = ((unsigned long long)g << 46)
                                  | ((unsigned long long)(unsigned)__float_as_int(lv) << 14)
                                  | (unsigned long long)(unsigned)lp;
            mbox_store(my_base + par * 8, pk);
        }
        unsigned long long v;
        int guard = 0;
        do {
            v = mbox_load(oth_base + par * 8);
        } while ((int)(v >> 46) != g && ++guard < (1 << 26));
        float pvf = __int_as_float((int)((v >> 14) & 0xFFFFFFFFull));
        int   pp  = (int)(v & 0x3FFFull);
        // combine: global argmax, tie -> lower flat index
        wp = (pvf > lv || (pvf == lv && pp < lp)) ? pp : lp;
        if (k == 0 && t == 0) {
            float* oc = centers + ((size_t)b * GG + g) * 3;
            oc[0] = PX[wp]; oc[1] = PY[wp]; oc[2] = PZ[wp];
        }
        // parity LDS buffers: write of par(g+2)==par(g) happens after
        // barrier(g+1), which follows every thread's scan at g -> race-free
    }
}

// ---------------------------------------------------------------------------
// KNN v3 + gather (unchanged math) + XCD swizzle: batch b's 512 blocks map
// to one XCD (blockIdx round-robins XCDs by %8) so the 196 KB SoA stays
// L2-resident per XCD. Per-round wave argmin via DPP.
// ---------------------------------------------------------------------------
__global__ __launch_bounds__(256, 8) void knn_kernel(const float* __restrict__ px,
                                                     const float* __restrict__ py,
                                                     const float* __restrict__ pz,
                                                     const float* __restrict__ x,
                                                     const float* __restrict__ centers,
                                                     float* __restrict__ out) {
    const int blk = blockIdx.x;
    const int bg  = ((blk & 7) << 9) | (blk >> 3);   // batch = blk&7 -> one XCD
    const int b   = bg >> 9;
    const int t   = threadIdx.x;

    const float* ctr = centers + (size_t)bg * 3;
    float cx = ctr[0], cy = ctr[1], cz = ctr[2];
    float cc2 = __fadd_rn(__fadd_rn(__fmul_rn(cx, cx), __fmul_rn(cy, cy)),
                          __fmul_rn(cz, cz));

    const float* PX = px + b * NN;
    const float* PY = py + b * NN;
    const float* PZ = pz + b * NN;

    float k1 = INFINITY, k2 = INFINITY;
    int   p1 = 0x7fffffff, p2 = 0x7fffffff;
    uint64_t mask = 0;   // consumed elements of my 64-pt chunk

#pragma unroll 4
    for (int i = 0; i < 64; ++i) {
        int pos = (i << 8) + t;           // coalesced
        float ax = PX[pos], ay = PY[pos], az = PZ[pos];
        float pp2 = __fadd_rn(__fadd_rn(__fmul_rn(ax, ax), __fmul_rn(ay, ay)),
                              __fmul_rn(az, az));
        float dot = fmaf(cz, az, fmaf(cy, ay, __fmul_rn(cx, ax)));
        float d2  = __fsub_rn(__fadd_rn(cc2, pp2), __fmul_rn(2.0f, dot));
        // ascending pos scan, strict '<': ties keep lower pos
        if (d2 < k1)      { k2 = k1; p2 = p1; k1 = d2; p1 = pos; }
        else if (d2 < k2) { k2 = d2; p2 = pos; }
    }

    __shared__ float s_v[2][4];
    __shared__ int   s_p[2][4];
    __shared__ int   s_chosen[KK];

    for (int j = 0; j < KK; ++j) {
        float v = k1; int vp = p1;
        // wave(64) DPP argmin, tie -> lower pos; result in lane 63
        wave_argmin_dpp(v, vp);
        int par = j & 1;
        if ((t & 63) == 63) { s_v[par][t >> 6] = v; s_p[par][t >> 6] = vp; }
        __syncthreads();
        // redundant scan of 4 partials by every thread
        float wv = s_v[par][0]; int wp = s_p[par][0];
#pragma unroll
        for (int q = 1; q < 4; ++q) {
            float qv = s_v[par][q]; int qp = s_p[par][q];
            if (qv < wv || (qv == wv && qp < wp)) { wv = qv; wp = qp; }
        }
        if (t == 0) s_chosen[j] = wp;
        if ((wp & 255) == t) {
            // I owned the extracted point: mark consumed, promote second
            mask |= 1ull << (wp >> 8);
            k1 = k2; p1 = p2;
            k2 = INFINITY; p2 = 0x7fffffff;
            if (p1 == 0x7fffffff && mask != 0xffffffffffffffffull) {
                // top-2 exhausted (rare): rebuild from unmasked points,
                // reloading coords from global; d2 bit-identical
                k1 = INFINITY;
#pragma unroll 1
                for (int i = 0; i < 64; ++i) {
                    if ((mask >> i) & 1ull) continue;
                    int pos = (i << 8) + t;
                    float ax = PX[pos], ay = PY[pos], az = PZ[pos];
                    float pp2 = __fadd_rn(__fadd_rn(__fmul_rn(ax, ax), __fmul_rn(ay, ay)),
                                          __fmul_rn(az, az));
                    float dot = fmaf(cz, az, fmaf(cy, ay, __fmul_rn(cx, ax)));
                    float d2  = __fsub_rn(__fadd_rn(cc2, pp2), __fmul_rn(2.0f, dot));
                    if (d2 < k1)      { k2 = k1; p2 = p1; k1 = d2; p1 = pos; }
                    else if (d2 < k2) { k2 = d2; p2 = pos; }
                }
            }
        }
        // no second barrier: parity buffer isolates next round's writes
    }
    __syncthreads();   // s_chosen visibility for gather

    // gather: 32 neighbors x 13 channels; subtract center from ch 4..6
    for (int v = t; v < KK * CC; v += 256) {
        int j = v / CC, c = v - j * CC;
        int pt = s_chosen[j] & (NN - 1);   // safety clamp (no-op when correct)
        float val = x[((size_t)b * NN + pt) * CC + c];
        if (c >= 4 && c < 7) {
            float cs = (c == 4) ? cx : ((c == 5) ? cy : cz);
            val = __fsub_rn(val, cs);
        }
        out[((size_t)bg * KK + j) * CC + c] = val;
    }
}

extern "C" void kernel_launch(void* const* d_in, const int* in_sizes, int n_in,
                              void* d_out, int out_size, void* d_ws, size_t ws_size,
                              hipStream_t stream) {
    const float* x = (const float*)d_in[0];
    float* out = (float*)d_out;
    float* centers = out + NEIGH_ELEMS;   // output 1 follows output 0, flat

    float* px = (float*)d_ws;
    float* py = px + BB * NN;
    float* pz = py + BB * NN;

    // fps mailbox lives in the first 2KB of the neighbor-output region;
    // pack zeroes it (stream-ordered before fps), knn overwrites it after.
    unsigned long long* mbox = (unsigned long long*)d_out;

    pack_kernel<<<(BB * NN + 255) / 256, 256, 0, stream>>>(x, px, py, pz, mbox);
    fps_kernel<<<2 * BB, 1024, 0, stream>>>(px, py, pz, centers, mbox);
    knn_kernel<<<BB * GG, 256, 0, stream>>>(px, py, pz, x, centers, out);
}